// Round 7
// baseline (182.904 us; speedup 1.0000x reference)
//
#include <hip/hip_runtime.h>

// Fixed-shape problem
#define NBATCH 4
#define NPTS   8192
#define MTGT   8192
#define BN     (NBATCH*NPTS)      // 32768 sources (== total targets)
#define TPB    256
#define SPT    16                 // sources per thread
#define SPB    (TPB*SPT)          // 4096 sources per block
#define NXBLK  (BN/SPB)           // 8
#define SEG    64                 // targets per block
#define NSEG   (MTGT/SEG)         // 128  -> grid 8x128 = 1024 blocks (4/CU)

// Monotone float->uint key: preserves float ordering under unsigned compare.
// atomicMin lattice -> bit-deterministic end state for any schedule
// (passed post-timing validation in rounds 1/2/5/6).
__device__ __forceinline__ unsigned f2key(float x) {
    unsigned u = __float_as_uint(x);
    return (u & 0x80000000u) ? ~u : (u | 0x80000000u);
}
__device__ __forceinline__ float key2f(unsigned k) {
    return __uint_as_float((k & 0x80000000u) ? (k ^ 0x80000000u) : ~k);
}

// Pack targets -> float4(x,y,z, valid ? ||t||^2 : 1e30) and init wsmin.
__global__ __launch_bounds__(256) void prep_kernel(const float* __restrict__ tgt,
                                                   float4* __restrict__ pt,
                                                   unsigned* __restrict__ wsmin) {
    int i = blockIdx.x * 256 + threadIdx.x;    // 0..BN-1 (BN == NBATCH*MTGT)
    float x = tgt[(size_t)i * 3 + 0];
    float y = tgt[(size_t)i * 3 + 1];
    float z = tgt[(size_t)i * 3 + 2];
    float tsq = fmaf(x, x, fmaf(y, y, z * z));
    bool valid = (x != 0.f) || (y != 0.f) || (z != 0.f);
    pt[i] = make_float4(x, y, z, valid ? tsq : 1e30f);
    wsmin[i] = 0xFFFFFFFFu;   // +inf in key space
}

// Per source point, min over one 64-target segment of d' = ||t||^2 - 2 s.t
// Targets read straight from global (wave-uniform address -> one 16B request,
// L1-resident); NO LDS -> no LDS-pipe bottleneck, no __syncthreads.
__global__ __launch_bounds__(TPB, 4) void nn_min_kernel(const float* __restrict__ src,
                                                        const float4* __restrict__ pt,
                                                        unsigned* __restrict__ wsmin) {
    const int tid = threadIdx.x;
    const int bx  = blockIdx.x;            // 0..7   (source slice)
    const int c   = blockIdx.y;            // 0..127 (target segment)
    const int b   = bx >> 1;               // 2 x-blocks per batch

    const float4* __restrict__ tseg = pt + (size_t)b * MTGT + (size_t)c * SEG;

    // ---- 16 source points: 12 contiguous float4 = 192 B per thread ----
    const int s0 = bx * SPB + tid * SPT;
    const float4* sv = reinterpret_cast<const float4*>(src + (size_t)s0 * 3);

    float ax[SPT], ay[SPT], az[SPT], bm[SPT];
#pragma unroll
    for (int g = 0; g < 4; ++g) {
        float4 a0 = sv[3 * g], a1 = sv[3 * g + 1], a2 = sv[3 * g + 2];
        ax[4*g+0] = -2.f*a0.x; ay[4*g+0] = -2.f*a0.y; az[4*g+0] = -2.f*a0.z;
        ax[4*g+1] = -2.f*a0.w; ay[4*g+1] = -2.f*a1.x; az[4*g+1] = -2.f*a1.y;
        ax[4*g+2] = -2.f*a1.z; ay[4*g+2] = -2.f*a1.w; az[4*g+2] = -2.f*a2.x;
        ax[4*g+3] = -2.f*a2.y; ay[4*g+3] = -2.f*a2.z; az[4*g+3] = -2.f*a2.w;
        bm[4*g+0] = 3e38f; bm[4*g+1] = 3e38f; bm[4*g+2] = 3e38f; bm[4*g+3] = 3e38f;
    }

    // ---- inner loop: 2 uniform 16B loads feed 112 VALU instructions ----
#pragma unroll 2
    for (int m = 0; m < SEG; m += 2) {
        float4 t0 = tseg[m], t1 = tseg[m + 1];
#pragma unroll
        for (int j = 0; j < SPT; ++j) {
            float d0 = fmaf(ax[j], t0.x, fmaf(ay[j], t0.y, fmaf(az[j], t0.z, t0.w)));
            float d1 = fmaf(ax[j], t1.x, fmaf(ay[j], t1.y, fmaf(az[j], t1.z, t1.w)));
            bm[j] = fminf(bm[j], fminf(d0, d1));
        }
    }

    // ---- combine: cached pre-check + atomicMin (stale >= current -> safe skip) ----
#pragma unroll
    for (int j = 0; j < SPT; ++j) {
        unsigned k = f2key(bm[j]);
        if (k < wsmin[s0 + j]) atomicMin(&wsmin[s0 + j], k);
    }
}

// 32 blocks: (batch, slice-of-1024-sources). Deterministic double partials.
__global__ __launch_bounds__(256) void reduce_kernel(const float* __restrict__ src,
                                                     const unsigned* __restrict__ wsmin,
                                                     double* __restrict__ partials) {
    const int blk = blockIdx.x;          // 0..31
    const int b = blk >> 3, slice = blk & 7;
    const int tid = threadIdx.x;

    double sum = 0.0, cnt = 0.0;
#pragma unroll
    for (int k = 0; k < 4; ++k) {
        int gid = b * NPTS + slice * 1024 + k * 256 + tid;
        float sx = src[(size_t)gid * 3 + 0];
        float sy = src[(size_t)gid * 3 + 1];
        float sz = src[(size_t)gid * 3 + 2];
        bool valid = (sx != 0.f) || (sy != 0.f) || (sz != 0.f);
        float ssq = fmaf(sx, sx, fmaf(sy, sy, sz * sz));
        float sq = fmaxf(0.f, ssq + key2f(wsmin[gid]));
        if (valid) { sum += (double)sq; cnt += 1.0; }
    }

    __shared__ double sh[512];
    sh[tid] = sum; sh[256 + tid] = cnt;
    __syncthreads();
    for (int s = 128; s > 0; s >>= 1) {
        if (tid < s) { sh[tid] += sh[tid + s]; sh[256 + tid] += sh[256 + tid + s]; }
        __syncthreads();
    }
    if (tid == 0) { partials[2 * blk] = sh[0]; partials[2 * blk + 1] = sh[256]; }
}

// Fixed-order final combine: bit-deterministic scalar output.
__global__ void final_kernel(const double* __restrict__ partials, float* __restrict__ out) {
    __shared__ double bmv[4];
    int t = threadIdx.x;
    if (t < 4) {
        double s = 0.0, c = 0.0;
        for (int i = 0; i < 8; ++i) {
            s += partials[2 * (t * 8 + i)];
            c += partials[2 * (t * 8 + i) + 1];
        }
        if (c < 1.0) c = 1.0;
        bmv[t] = s / (3.0 * c);
    }
    __syncthreads();
    if (t == 0) out[0] = (float)((bmv[0] + bmv[1] + bmv[2] + bmv[3]) * 0.25);
}

extern "C" void kernel_launch(void* const* d_in, const int* in_sizes, int n_in,
                              void* d_out, int out_size, void* d_ws, size_t ws_size,
                              hipStream_t stream) {
    const float* src = (const float*)d_in[0];
    const float* tgt = (const float*)d_in[1];
    float* out = (float*)d_out;

    float4*   pt       = (float4*)d_ws;                                   // 512 KiB
    unsigned* wsmin    = (unsigned*)((char*)d_ws + (size_t)BN * 16);      // 128 KiB
    double*   partials = (double*)((char*)d_ws + (size_t)BN * 16 + (size_t)BN * 4);

    prep_kernel<<<dim3(BN / 256), dim3(256), 0, stream>>>(tgt, pt, wsmin);
    nn_min_kernel<<<dim3(NXBLK, NSEG), dim3(TPB), 0, stream>>>(src, pt, wsmin);
    reduce_kernel<<<dim3(32), dim3(256), 0, stream>>>(src, wsmin, partials);
    final_kernel<<<dim3(1), dim3(64), 0, stream>>>(partials, out);
}